// Round 5
// baseline (129.397 us; speedup 1.0000x reference)
//
#include <hip/hip_runtime.h>
#include <stdint.h>

// out[b,i,s] = (||w_i||^2 - 2*sum_o w[i,o]x[b,o,s] + ||x_{b,:,s}||^2) / K
// B=4, M=4096, K=1024, N=2048. fp32 in/out. bf16 16x16x32 MFMA cross term.
// Round-2 verified GEMM (256x256, BK=32, 8 waves, quad-buffer, 2-phase,
// counted vmcnt(8), XOR swizzle -> 0 bank conflicts) + nt stores/loads,
// memset folded into prep_w.

#define M_DIM 4096
#define K_DIM 1024
#define N_DIM 2048
#define B_DIM 4

#define BM 256
#define BN 256
#define BK 32
#define NKT (K_DIM / BK)  // 32
#define MT (M_DIM / BM)   // 16
#define NT (N_DIM / BN)   // 8

typedef __attribute__((ext_vector_type(8))) __bf16 bf16x8;
typedef __attribute__((ext_vector_type(4))) float f32x4;
typedef __attribute__((ext_vector_type(4))) float f32x4v;

__device__ __forceinline__ ushort f2bf(float f) {
  uint32_t u = __float_as_uint(f);
  uint32_t r = (u + 0x7fffu + ((u >> 16) & 1u)) >> 16;  // RNE
  return (ushort)r;
}
__device__ __forceinline__ float bf2f(ushort u) {
  return __uint_as_float(((uint32_t)u) << 16);
}

// -------- prep_w (also zeroes x2 for prep_x's atomics) -----------------------
__global__ __launch_bounds__(256) void prep_w(const float* __restrict__ w,
                                              ushort* __restrict__ wbf,
                                              float* __restrict__ w2,
                                              float* __restrict__ x2) {
  const int i = blockIdx.x;
  const int t = threadIdx.x;
  if (i < 32) x2[i * 256 + t] = 0.0f;  // 8192 floats zeroed by blocks 0-31
  f32x4v v = __builtin_nontemporal_load(((const f32x4v*)(w + (size_t)i * K_DIM)) + t);
  float ss = v.x * v.x + v.y * v.y + v.z * v.z + v.w * v.w;
  ushort4 o = make_ushort4(f2bf(v.x), f2bf(v.y), f2bf(v.z), f2bf(v.w));
  ((ushort4*)(wbf + (size_t)i * K_DIM))[t] = o;
#pragma unroll
  for (int off = 32; off > 0; off >>= 1) ss += __shfl_down(ss, off);
  __shared__ float red[4];
  if ((t & 63) == 0) red[t >> 6] = ss;
  __syncthreads();
  if (t == 0) w2[i] = red[0] + red[1] + red[2] + red[3];
}

// -------- prep_x -------------------------------------------------------------
__global__ __launch_bounds__(256) void prep_x(const float* __restrict__ x,
                                              ushort* __restrict__ xbT,
                                              float* __restrict__ x2) {
  __shared__ ushort tile[64][68];
  const int b = blockIdx.z;
  const int o0 = blockIdx.y * 64;
  const int s0 = blockIdx.x * 64;
  const int t = threadIdx.x;
  const int tr = t >> 4;
  const int tc = t & 15;
#pragma unroll
  for (int p = 0; p < 4; ++p) {
    const int r = p * 16 + tr;
    f32x4v v = __builtin_nontemporal_load(
        ((const f32x4v*)(x + ((size_t)(b * K_DIM + o0 + r)) * N_DIM + s0)) + tc);
    tile[r][tc * 4 + 0] = f2bf(v.x);
    tile[r][tc * 4 + 1] = f2bf(v.y);
    tile[r][tc * 4 + 2] = f2bf(v.z);
    tile[r][tc * 4 + 3] = f2bf(v.w);
  }
  __syncthreads();
#pragma unroll
  for (int p = 0; p < 4; ++p) {
    const int s = p * 16 + tr;
    ushort u0 = tile[tc * 4 + 0][s];
    ushort u1 = tile[tc * 4 + 1][s];
    ushort u2 = tile[tc * 4 + 2][s];
    ushort u3 = tile[tc * 4 + 3][s];
    float f0 = bf2f(u0), f1 = bf2f(u1), f2 = bf2f(u2), f3 = bf2f(u3);
    float ss = f0 * f0 + f1 * f1 + f2 * f2 + f3 * f3;
#pragma unroll
    for (int m = 1; m < 16; m <<= 1) ss += __shfl_xor(ss, m);
    if (tc == 0) atomicAdd(&x2[b * N_DIM + s0 + s], ss);
    *(ushort4*)(xbT + ((size_t)(b * N_DIM + s0 + s)) * K_DIM + o0 + tc * 4) =
        make_ushort4(u0, u1, u2, u3);
  }
}

// -------- GEMM (round-2 verified structure) ----------------------------------
typedef const __attribute__((address_space(1))) uint32_t* gp_t;
typedef __attribute__((address_space(3))) uint32_t* lp_t;

__device__ __forceinline__ void gload_lds16(const void* g, const void* l) {
  __builtin_amdgcn_global_load_lds((gp_t)(uintptr_t)g,
                                   (lp_t)(uint32_t)(uintptr_t)l, 16, 0, 0);
}

#define MFMA(a, b, c) __builtin_amdgcn_mfma_f32_16x16x32_bf16((a), (b), (c), 0, 0, 0)
#define FENCE() asm volatile("" ::: "memory")

__global__ __launch_bounds__(512, 2) void gemm_mse(
    const ushort* __restrict__ wbf, const ushort* __restrict__ xbT,
    const float* __restrict__ w2, const float* __restrict__ x2,
    float* __restrict__ out) {
  // LDS: A bufs 4x16KB at [0,64K), B bufs 4x16KB at [64K,128K)
  __shared__ __align__(16) char smem[131072];
  const int tid = threadIdx.x;
  const int wid = tid >> 6;
  const int lane = tid & 63;
  const int laneR = lane & 15;
  const int g = lane >> 4;
  const int wm = wid >> 2;  // 0..1
  const int wn = wid & 3;   // 0..3

  // XCD-aware block swizzle (512 blocks, 512%8==0 -> bijective)
  const int bid = blockIdx.x;
  const int swz = (bid & 7) * (MT * NT * B_DIM / 8) + (bid >> 3);
  const int m = swz & (MT - 1);
  const int nb = swz >> 4;
  const int n = nb & (NT - 1);
  const int bz = nb >> 3;

  const ushort* Ag = wbf + (size_t)m * BM * K_DIM;
  const ushort* Bg = xbT + ((size_t)bz * N_DIM + (size_t)n * BN) * K_DIM;

  // staging: slot s -> phys byte p=s*16; lin = p ^ (((p>>7)&3)<<4);
  // row = lin>>6 (64B = one 32-bf16 row), col = (lin&63)>>1
  const int p0 = tid * 16, p1 = (tid + 512) * 16;
  const int li0 = p0 ^ (((p0 >> 7) & 3) << 4);
  const int li1 = p1 ^ (((p1 >> 7) & 3) << 4);
  const size_t gOff0 = (size_t)(li0 >> 6) * K_DIM + ((li0 & 63) >> 1);
  const size_t gOff1 = (size_t)(li1 >> 6) * K_DIM + ((li1 & 63) >> 1);
  const int stA0 = wid * 1024, stA1 = 8192 + wid * 1024;
  const int stB0 = 65536 + wid * 1024, stB1 = 65536 + 8192 + wid * 1024;

#define STAGE_A(tt)                                    \
  {                                                    \
    const int bo_ = ((tt) & 3) * 16384;                \
    const int ko_ = (tt) * BK;                         \
    gload_lds16(Ag + gOff0 + ko_, smem + bo_ + stA0);  \
    gload_lds16(Ag + gOff1 + ko_, smem + bo_ + stA1);  \
  }
#define STAGE_B(tt)                                    \
  {                                                    \
    const int bo_ = ((tt) & 3) * 16384;                \
    const int ko_ = (tt) * BK;                         \
    gload_lds16(Bg + gOff0 + ko_, smem + bo_ + stB0);  \
    gload_lds16(Bg + gOff1 + ko_, smem + bo_ + stB1);  \
  }

  // frag bases: row-major [row][32 bf16]; mask = ((laneR>>1)&3)<<4
  const int mask = ((laneR >> 1) & 3) << 4;
  const int baseA = ((((wm * 128 + laneR) << 6) | (g << 4)) ^ mask);
  const int baseB = 65536 + ((((wn * 64 + laneR) << 6) | (g << 4)) ^ mask);

#define LDA(mi, bo) (*(const bf16x8*)(smem + (bo) + baseA + (mi)*1024))
#define LDB(ni, bo) (*(const bf16x8*)(smem + (bo) + baseB + (ni)*1024))

  f32x4 acc[8][4] = {};

  // prologue: stage tiles 0,1,2; tile 0 landed at vmcnt(8)
  STAGE_A(0); STAGE_B(0);
  STAGE_A(1); STAGE_B(1);
  STAGE_A(2); STAGE_B(2);
  asm volatile("s_waitcnt vmcnt(8)" ::: "memory");
  __builtin_amdgcn_s_barrier();
  FENCE();

  for (int t = 0; t < NKT; ++t) {
    const int bo = (t & 3) * 16384;
    // ======== phase 1: frag-read A[0-3],B[0-3]; stage A(t+3); mfma Q-low ====
    bf16x8 a0 = LDA(0, bo), a1 = LDA(1, bo), a2 = LDA(2, bo), a3 = LDA(3, bo);
    bf16x8 b0 = LDB(0, bo), b1 = LDB(1, bo), b2 = LDB(2, bo), b3 = LDB(3, bo);
    if (t < NKT - 3) STAGE_A(t + 3);
    FENCE();
    __builtin_amdgcn_s_barrier();
    FENCE();
    __builtin_amdgcn_s_setprio(1);
    acc[0][0] = MFMA(a0, b0, acc[0][0]);
    acc[0][1] = MFMA(a0, b1, acc[0][1]);
    acc[0][2] = MFMA(a0, b2, acc[0][2]);
    acc[0][3] = MFMA(a0, b3, acc[0][3]);
    acc[1][0] = MFMA(a1, b0, acc[1][0]);
    acc[1][1] = MFMA(a1, b1, acc[1][1]);
    acc[1][2] = MFMA(a1, b2, acc[1][2]);
    acc[1][3] = MFMA(a1, b3, acc[1][3]);
    acc[2][0] = MFMA(a2, b0, acc[2][0]);
    acc[2][1] = MFMA(a2, b1, acc[2][1]);
    acc[2][2] = MFMA(a2, b2, acc[2][2]);
    acc[2][3] = MFMA(a2, b3, acc[2][3]);
    acc[3][0] = MFMA(a3, b0, acc[3][0]);
    acc[3][1] = MFMA(a3, b1, acc[3][1]);
    acc[3][2] = MFMA(a3, b2, acc[3][2]);
    acc[3][3] = MFMA(a3, b3, acc[3][3]);
    __builtin_amdgcn_s_setprio(0);
    FENCE();
    __builtin_amdgcn_s_barrier();
    FENCE();
    // ======== phase 2: frag-read A[4-7]; stage B(t+3); vmcnt(8); mfma Q-high
    bf16x8 a4 = LDA(4, bo), a5 = LDA(5, bo), a6 = LDA(6, bo), a7 = LDA(7, bo);
    if (t < NKT - 3) STAGE_B(t + 3);
    // counted wait: 8 outstanding = tiles t+2,t+3 in flight; tile t+1 landed.
    asm volatile("s_waitcnt vmcnt(8)" ::: "memory");
    __builtin_amdgcn_s_barrier();
    FENCE();
    __builtin_amdgcn_s_setprio(1);
    acc[4][0] = MFMA(a4, b0, acc[4][0]);
    acc[4][1] = MFMA(a4, b1, acc[4][1]);
    acc[4][2] = MFMA(a4, b2, acc[4][2]);
    acc[4][3] = MFMA(a4, b3, acc[4][3]);
    acc[5][0] = MFMA(a5, b0, acc[5][0]);
    acc[5][1] = MFMA(a5, b1, acc[5][1]);
    acc[5][2] = MFMA(a5, b2, acc[5][2]);
    acc[5][3] = MFMA(a5, b3, acc[5][3]);
    acc[6][0] = MFMA(a6, b0, acc[6][0]);
    acc[6][1] = MFMA(a6, b1, acc[6][1]);
    acc[6][2] = MFMA(a6, b2, acc[6][2]);
    acc[6][3] = MFMA(a6, b3, acc[6][3]);
    acc[7][0] = MFMA(a7, b0, acc[7][0]);
    acc[7][1] = MFMA(a7, b1, acc[7][1]);
    acc[7][2] = MFMA(a7, b2, acc[7][2]);
    acc[7][3] = MFMA(a7, b3, acc[7][3]);
    __builtin_amdgcn_s_setprio(0);
    FENCE();
    __builtin_amdgcn_s_barrier();
    FENCE();
  }

  // epilogue: out = (w2[i] - 2*acc + x2[b,s]) / K, nontemporal stores
  const float inv = 1.0f / (float)K_DIM;
  const int rowb = m * BM + wm * 128 + g * 4;  // + mi*16 + j
  const int colb = n * BN + wn * 64 + laneR;   // + ni*16
  float xv[4];
#pragma unroll
  for (int ni = 0; ni < 4; ++ni) xv[ni] = x2[bz * N_DIM + colb + ni * 16];
  float* outp = out + (size_t)bz * M_DIM * N_DIM;
#pragma unroll
  for (int mi = 0; mi < 8; ++mi) {
#pragma unroll
    for (int j = 0; j < 4; ++j) {
      const int row = rowb + mi * 16 + j;
      const float wv = w2[row];
      float* orow = outp + (size_t)row * N_DIM + colb;
#pragma unroll
      for (int ni = 0; ni < 4; ++ni)
        __builtin_nontemporal_store((wv - 2.0f * acc[mi][ni][j] + xv[ni]) * inv,
                                    orow + ni * 16);
    }
  }
#undef STAGE_A
#undef STAGE_B
#undef LDA
#undef LDB
}

// -------- launcher -----------------------------------------------------------
extern "C" void kernel_launch(void* const* d_in, const int* in_sizes, int n_in,
                              void* d_out, int out_size, void* d_ws, size_t ws_size,
                              hipStream_t stream) {
  const float* x = (const float*)d_in[0];  // (4, 1024, 2048)
  const float* w = (const float*)d_in[1];  // (4096, 1024)
  float* out = (float*)d_out;              // (4, 4096, 2048)
  char* ws = (char*)d_ws;
  ushort* wbf = (ushort*)ws;                        // 8 MB
  ushort* xbT = (ushort*)(ws + (size_t)(8 << 20));  // 16 MB
  float* w2 = (float*)(ws + (size_t)(24 << 20));    // 16 KB
  float* x2 = w2 + M_DIM;                           // 32 KB

  prep_w<<<dim3(M_DIM), dim3(256), 0, stream>>>(w, wbf, w2, x2);
  prep_x<<<dim3(N_DIM / 64, K_DIM / 64, B_DIM), dim3(256), 0, stream>>>(x, xbT, x2);
  gemm_mse<<<dim3(MT * NT * B_DIM), dim3(512), 0, stream>>>(wbf, xbT, w2, x2, out);
}

// Round 6
// 116.762 us; speedup vs baseline: 1.1082x; 1.1082x over previous
//
#include <hip/hip_runtime.h>
#include <stdint.h>

// out[b,i,s] = (||w_i||^2 - 2*sum_o w[i,o]x[b,o,s] + ||x_{b,:,s}||^2) / K
// B=4, M=4096, K=1024, N=2048. fp32 in/out. bf16 16x16x32 MFMA cross term.
// K-loop = round-2 verified structure (256x256, BK=32, 8 waves, quad-buffer,
// 2-phase, counted vmcnt(8), XOR swizzle -> 0 bank conflicts).
// NEW: LDS-transpose epilogue -> coalesced 256B nontemporal dwordx4 stores.

#define M_DIM 4096
#define K_DIM 1024
#define N_DIM 2048
#define B_DIM 4

#define BM 256
#define BN 256
#define BK 32
#define NKT (K_DIM / BK)  // 32
#define MT (M_DIM / BM)   // 16
#define NT (N_DIM / BN)   // 8

typedef __attribute__((ext_vector_type(8))) __bf16 bf16x8;
typedef __attribute__((ext_vector_type(4))) float f32x4;
typedef __attribute__((ext_vector_type(4))) float f32x4v;

__device__ __forceinline__ ushort f2bf(float f) {
  uint32_t u = __float_as_uint(f);
  uint32_t r = (u + 0x7fffu + ((u >> 16) & 1u)) >> 16;  // RNE
  return (ushort)r;
}
__device__ __forceinline__ float bf2f(ushort u) {
  return __uint_as_float(((uint32_t)u) << 16);
}

// -------- prep_w (also zeroes x2 for prep_x's atomics) -----------------------
__global__ __launch_bounds__(256) void prep_w(const float* __restrict__ w,
                                              ushort* __restrict__ wbf,
                                              float* __restrict__ w2,
                                              float* __restrict__ x2) {
  const int i = blockIdx.x;
  const int t = threadIdx.x;
  if (i < 32) x2[i * 256 + t] = 0.0f;  // 8192 floats zeroed by blocks 0-31
  f32x4v v = __builtin_nontemporal_load(((const f32x4v*)(w + (size_t)i * K_DIM)) + t);
  float ss = v.x * v.x + v.y * v.y + v.z * v.z + v.w * v.w;
  ushort4 o = make_ushort4(f2bf(v.x), f2bf(v.y), f2bf(v.z), f2bf(v.w));
  ((ushort4*)(wbf + (size_t)i * K_DIM))[t] = o;
#pragma unroll
  for (int off = 32; off > 0; off >>= 1) ss += __shfl_down(ss, off);
  __shared__ float red[4];
  if ((t & 63) == 0) red[t >> 6] = ss;
  __syncthreads();
  if (t == 0) w2[i] = red[0] + red[1] + red[2] + red[3];
}

// -------- prep_x -------------------------------------------------------------
__global__ __launch_bounds__(256) void prep_x(const float* __restrict__ x,
                                              ushort* __restrict__ xbT,
                                              float* __restrict__ x2) {
  __shared__ ushort tile[64][68];
  const int b = blockIdx.z;
  const int o0 = blockIdx.y * 64;
  const int s0 = blockIdx.x * 64;
  const int t = threadIdx.x;
  const int tr = t >> 4;
  const int tc = t & 15;
#pragma unroll
  for (int p = 0; p < 4; ++p) {
    const int r = p * 16 + tr;
    f32x4v v = __builtin_nontemporal_load(
        ((const f32x4v*)(x + ((size_t)(b * K_DIM + o0 + r)) * N_DIM + s0)) + tc);
    tile[r][tc * 4 + 0] = f2bf(v.x);
    tile[r][tc * 4 + 1] = f2bf(v.y);
    tile[r][tc * 4 + 2] = f2bf(v.z);
    tile[r][tc * 4 + 3] = f2bf(v.w);
  }
  __syncthreads();
#pragma unroll
  for (int p = 0; p < 4; ++p) {
    const int s = p * 16 + tr;
    ushort u0 = tile[tc * 4 + 0][s];
    ushort u1 = tile[tc * 4 + 1][s];
    ushort u2 = tile[tc * 4 + 2][s];
    ushort u3 = tile[tc * 4 + 3][s];
    float f0 = bf2f(u0), f1 = bf2f(u1), f2 = bf2f(u2), f3 = bf2f(u3);
    float ss = f0 * f0 + f1 * f1 + f2 * f2 + f3 * f3;
#pragma unroll
    for (int m = 1; m < 16; m <<= 1) ss += __shfl_xor(ss, m);
    if (tc == 0) atomicAdd(&x2[b * N_DIM + s0 + s], ss);
    *(ushort4*)(xbT + ((size_t)(b * N_DIM + s0 + s)) * K_DIM + o0 + tc * 4) =
        make_ushort4(u0, u1, u2, u3);
  }
}

// -------- GEMM ---------------------------------------------------------------
typedef const __attribute__((address_space(1))) uint32_t* gp_t;
typedef __attribute__((address_space(3))) uint32_t* lp_t;

__device__ __forceinline__ void gload_lds16(const void* g, const void* l) {
  __builtin_amdgcn_global_load_lds((gp_t)(uintptr_t)g,
                                   (lp_t)(uint32_t)(uintptr_t)l, 16, 0, 0);
}

#define MFMA(a, b, c) __builtin_amdgcn_mfma_f32_16x16x32_bf16((a), (b), (c), 0, 0, 0)
#define FENCE() asm volatile("" ::: "memory")

__global__ __launch_bounds__(512, 2) void gemm_mse(
    const ushort* __restrict__ wbf, const ushort* __restrict__ xbT,
    const float* __restrict__ w2, const float* __restrict__ x2,
    float* __restrict__ out) {
  // LDS: A bufs 4x16KB at [0,64K), B bufs 4x16KB at [64K,128K)
  __shared__ __align__(16) char smem[131072];
  const int tid = threadIdx.x;
  const int wid = tid >> 6;
  const int lane = tid & 63;
  const int laneR = lane & 15;
  const int g = lane >> 4;
  const int wm = wid >> 2;  // 0..1
  const int wn = wid & 3;   // 0..3

  // XCD-aware block swizzle (512 blocks, 512%8==0 -> bijective)
  const int bid = blockIdx.x;
  const int swz = (bid & 7) * (MT * NT * B_DIM / 8) + (bid >> 3);
  const int m = swz & (MT - 1);
  const int nb = swz >> 4;
  const int n = nb & (NT - 1);
  const int bz = nb >> 3;

  const ushort* Ag = wbf + (size_t)m * BM * K_DIM;
  const ushort* Bg = xbT + ((size_t)bz * N_DIM + (size_t)n * BN) * K_DIM;

  // staging: slot s -> phys byte p=s*16; lin = p ^ (((p>>7)&3)<<4);
  // row = lin>>6 (64B = one 32-bf16 row), col = (lin&63)>>1
  const int p0 = tid * 16, p1 = (tid + 512) * 16;
  const int li0 = p0 ^ (((p0 >> 7) & 3) << 4);
  const int li1 = p1 ^ (((p1 >> 7) & 3) << 4);
  const size_t gOff0 = (size_t)(li0 >> 6) * K_DIM + ((li0 & 63) >> 1);
  const size_t gOff1 = (size_t)(li1 >> 6) * K_DIM + ((li1 & 63) >> 1);
  const int stA0 = wid * 1024, stA1 = 8192 + wid * 1024;
  const int stB0 = 65536 + wid * 1024, stB1 = 65536 + 8192 + wid * 1024;

#define STAGE_A(tt)                                    \
  {                                                    \
    const int bo_ = ((tt) & 3) * 16384;                \
    const int ko_ = (tt) * BK;                         \
    gload_lds16(Ag + gOff0 + ko_, smem + bo_ + stA0);  \
    gload_lds16(Ag + gOff1 + ko_, smem + bo_ + stA1);  \
  }
#define STAGE_B(tt)                                    \
  {                                                    \
    const int bo_ = ((tt) & 3) * 16384;                \
    const int ko_ = (tt) * BK;                         \
    gload_lds16(Bg + gOff0 + ko_, smem + bo_ + stB0);  \
    gload_lds16(Bg + gOff1 + ko_, smem + bo_ + stB1);  \
  }

  // frag bases: row-major [row][32 bf16]; mask = ((laneR>>1)&3)<<4
  const int mask = ((laneR >> 1) & 3) << 4;
  const int baseA = ((((wm * 128 + laneR) << 6) | (g << 4)) ^ mask);
  const int baseB = 65536 + ((((wn * 64 + laneR) << 6) | (g << 4)) ^ mask);

#define LDA(mi, bo) (*(const bf16x8*)(smem + (bo) + baseA + (mi)*1024))
#define LDB(ni, bo) (*(const bf16x8*)(smem + (bo) + baseB + (ni)*1024))

  f32x4 acc[8][4] = {};

  // prologue: stage tiles 0,1,2; tile 0 landed at vmcnt(8)
  STAGE_A(0); STAGE_B(0);
  STAGE_A(1); STAGE_B(1);
  STAGE_A(2); STAGE_B(2);
  asm volatile("s_waitcnt vmcnt(8)" ::: "memory");
  __builtin_amdgcn_s_barrier();
  FENCE();

  for (int t = 0; t < NKT; ++t) {
    const int bo = (t & 3) * 16384;
    // ======== phase 1: frag-read A[0-3],B[0-3]; stage A(t+3); mfma Q-low ====
    bf16x8 a0 = LDA(0, bo), a1 = LDA(1, bo), a2 = LDA(2, bo), a3 = LDA(3, bo);
    bf16x8 b0 = LDB(0, bo), b1 = LDB(1, bo), b2 = LDB(2, bo), b3 = LDB(3, bo);
    if (t < NKT - 3) STAGE_A(t + 3);
    FENCE();
    __builtin_amdgcn_s_barrier();
    FENCE();
    __builtin_amdgcn_s_setprio(1);
    acc[0][0] = MFMA(a0, b0, acc[0][0]);
    acc[0][1] = MFMA(a0, b1, acc[0][1]);
    acc[0][2] = MFMA(a0, b2, acc[0][2]);
    acc[0][3] = MFMA(a0, b3, acc[0][3]);
    acc[1][0] = MFMA(a1, b0, acc[1][0]);
    acc[1][1] = MFMA(a1, b1, acc[1][1]);
    acc[1][2] = MFMA(a1, b2, acc[1][2]);
    acc[1][3] = MFMA(a1, b3, acc[1][3]);
    acc[2][0] = MFMA(a2, b0, acc[2][0]);
    acc[2][1] = MFMA(a2, b1, acc[2][1]);
    acc[2][2] = MFMA(a2, b2, acc[2][2]);
    acc[2][3] = MFMA(a2, b3, acc[2][3]);
    acc[3][0] = MFMA(a3, b0, acc[3][0]);
    acc[3][1] = MFMA(a3, b1, acc[3][1]);
    acc[3][2] = MFMA(a3, b2, acc[3][2]);
    acc[3][3] = MFMA(a3, b3, acc[3][3]);
    __builtin_amdgcn_s_setprio(0);
    FENCE();
    __builtin_amdgcn_s_barrier();
    FENCE();
    // ======== phase 2: frag-read A[4-7]; stage B(t+3); vmcnt(8); mfma Q-high
    bf16x8 a4 = LDA(4, bo), a5 = LDA(5, bo), a6 = LDA(6, bo), a7 = LDA(7, bo);
    if (t < NKT - 3) STAGE_B(t + 3);
    // counted wait: 8 outstanding = tiles t+2,t+3 in flight; tile t+1 landed.
    asm volatile("s_waitcnt vmcnt(8)" ::: "memory");
    __builtin_amdgcn_s_barrier();
    FENCE();
    __builtin_amdgcn_s_setprio(1);
    acc[4][0] = MFMA(a4, b0, acc[4][0]);
    acc[4][1] = MFMA(a4, b1, acc[4][1]);
    acc[4][2] = MFMA(a4, b2, acc[4][2]);
    acc[4][3] = MFMA(a4, b3, acc[4][3]);
    acc[5][0] = MFMA(a5, b0, acc[5][0]);
    acc[5][1] = MFMA(a5, b1, acc[5][1]);
    acc[5][2] = MFMA(a5, b2, acc[5][2]);
    acc[5][3] = MFMA(a5, b3, acc[5][3]);
    acc[6][0] = MFMA(a6, b0, acc[6][0]);
    acc[6][1] = MFMA(a6, b1, acc[6][1]);
    acc[6][2] = MFMA(a6, b2, acc[6][2]);
    acc[6][3] = MFMA(a6, b3, acc[6][3]);
    acc[7][0] = MFMA(a7, b0, acc[7][0]);
    acc[7][1] = MFMA(a7, b1, acc[7][1]);
    acc[7][2] = MFMA(a7, b2, acc[7][2]);
    acc[7][3] = MFMA(a7, b3, acc[7][3]);
    __builtin_amdgcn_s_setprio(0);
    FENCE();
    __builtin_amdgcn_s_barrier();
    FENCE();
  }

  // ==== epilogue: LDS-transpose -> coalesced nontemporal dwordx4 stores =====
  // Drain staging (up to 8 in-flight gload_lds still target LDS) then reuse
  // LDS as per-wave 64x64 f32 transpose buffers (16 KB/wave, no cross-wave
  // sharing -> no further barriers needed).
  asm volatile("s_waitcnt vmcnt(0)" ::: "memory");
  __builtin_amdgcn_s_barrier();
  FENCE();

  const float inv = 1.0f / (float)K_DIM;
  const int rowb0 = m * BM + wm * 128;  // wave's global row base
  const int colb0 = n * BN + wn * 64;   // wave's global col base
  float xv[4];
#pragma unroll
  for (int ni = 0; ni < 4; ++ni) xv[ni] = x2[bz * N_DIM + colb0 + ni * 16 + laneR];
  float* lds_f = (float*)smem + wid * 4096;  // 16 KB per wave
  float* outp = out + (size_t)bz * M_DIM * N_DIM;

#pragma unroll
  for (int miH = 0; miH < 2; ++miH) {
    // -- write pass: value transform + transposed, bank-swizzled scatter.
    // local row r = mi4*16 + g*4 + j (0..63), col c = ni*16+laneR;
    // word = r*64 + (c ^ ((r&7)<<2))  -> ~2-way banks on write,
    // 8-lanes/quad (floor) on b128 read.
#pragma unroll
    for (int mi4 = 0; mi4 < 4; ++mi4) {
      const int mi = miH * 4 + mi4;
#pragma unroll
      for (int j = 0; j < 4; ++j) {
        const int r = mi4 * 16 + g * 4 + j;
        const float wv = w2[rowb0 + miH * 64 + r];
#pragma unroll
        for (int ni = 0; ni < 4; ++ni) {
          const int c = ni * 16 + laneR;
          lds_f[r * 64 + (c ^ ((r & 7) << 2))] =
              (wv - 2.0f * acc[mi][ni][j] + xv[ni]) * inv;
        }
      }
    }
    // -- read+store pass: lane covers row (lane>>4)+4k, cols (lane&15)*4..+3;
    // each instr stores 4 rows x 256B contiguous -> clean nt bursts.
#pragma unroll
    for (int k = 0; k < 16; ++k) {
      const int r = k * 4 + (lane >> 4);
      const int c0 = laneR * 4;
      f32x4 v = *(const f32x4*)&lds_f[r * 64 + (c0 ^ ((r & 7) << 2))];
      __builtin_nontemporal_store(
          v, (f32x4*)(outp + (size_t)(rowb0 + miH * 64 + r) * N_DIM + colb0 + c0));
    }
  }
#undef STAGE_A
#undef STAGE_B
#undef LDA
#undef LDB
}

// -------- launcher -----------------------------------------------------------
extern "C" void kernel_launch(void* const* d_in, const int* in_sizes, int n_in,
                              void* d_out, int out_size, void* d_ws, size_t ws_size,
                              hipStream_t stream) {
  const float* x = (const float*)d_in[0];  // (4, 1024, 2048)
  const float* w = (const float*)d_in[1];  // (4096, 1024)
  float* out = (float*)d_out;              // (4, 4096, 2048)
  char* ws = (char*)d_ws;
  ushort* wbf = (ushort*)ws;                        // 8 MB
  ushort* xbT = (ushort*)(ws + (size_t)(8 << 20));  // 16 MB
  float* w2 = (float*)(ws + (size_t)(24 << 20));    // 16 KB
  float* x2 = w2 + M_DIM;                           // 32 KB

  prep_w<<<dim3(M_DIM), dim3(256), 0, stream>>>(w, wbf, w2, x2);
  prep_x<<<dim3(N_DIM / 64, K_DIM / 64, B_DIM), dim3(256), 0, stream>>>(x, xbT, x2);
  gemm_mse<<<dim3(MT * NT * B_DIM), dim3(512), 0, stream>>>(wbf, xbT, w2, x2, out);
}

// Round 7
// 102.373 us; speedup vs baseline: 1.2640x; 1.1406x over previous
//
#include <hip/hip_runtime.h>
#include <stdint.h>

// out[b,i,s] = (||w_i||^2 - 2*sum_o w[i,o]x[b,o,s] + ||x_{b,:,s}||^2) / K
// B=4, M=4096, K=1024, N=2048. fp32 in/out. bf16 16x16x32 MFMA cross term.
// 256x256 tile, BK=32, 8 waves, quad-buffer, XOR swizzle (0 conflicts).
// R7: ONE barrier + ONE counted vmcnt(8) per K-tile (uniform wraparound
// staging ledger); LDS-transpose epilogue with NORMAL stores (L2-absorbed).

#define M_DIM 4096
#define K_DIM 1024
#define N_DIM 2048
#define B_DIM 4

#define BM 256
#define BN 256
#define BK 32
#define NKT (K_DIM / BK)  // 32
#define MT (M_DIM / BM)   // 16
#define NT (N_DIM / BN)   // 8

typedef __attribute__((ext_vector_type(8))) __bf16 bf16x8;
typedef __attribute__((ext_vector_type(4))) float f32x4;
typedef __attribute__((ext_vector_type(4))) float f32x4v;

__device__ __forceinline__ ushort f2bf(float f) {
  uint32_t u = __float_as_uint(f);
  uint32_t r = (u + 0x7fffu + ((u >> 16) & 1u)) >> 16;  // RNE
  return (ushort)r;
}
__device__ __forceinline__ float bf2f(ushort u) {
  return __uint_as_float(((uint32_t)u) << 16);
}

// -------- prep_w (also zeroes x2 for prep_x's atomics) -----------------------
__global__ __launch_bounds__(256) void prep_w(const float* __restrict__ w,
                                              ushort* __restrict__ wbf,
                                              float* __restrict__ w2,
                                              float* __restrict__ x2) {
  const int i = blockIdx.x;
  const int t = threadIdx.x;
  if (i < 32) x2[i * 256 + t] = 0.0f;  // 8192 floats zeroed by blocks 0-31
  f32x4v v = __builtin_nontemporal_load(((const f32x4v*)(w + (size_t)i * K_DIM)) + t);
  float ss = v.x * v.x + v.y * v.y + v.z * v.z + v.w * v.w;
  ushort4 o = make_ushort4(f2bf(v.x), f2bf(v.y), f2bf(v.z), f2bf(v.w));
  ((ushort4*)(wbf + (size_t)i * K_DIM))[t] = o;
#pragma unroll
  for (int off = 32; off > 0; off >>= 1) ss += __shfl_down(ss, off);
  __shared__ float red[4];
  if ((t & 63) == 0) red[t >> 6] = ss;
  __syncthreads();
  if (t == 0) w2[i] = red[0] + red[1] + red[2] + red[3];
}

// -------- prep_x -------------------------------------------------------------
__global__ __launch_bounds__(256) void prep_x(const float* __restrict__ x,
                                              ushort* __restrict__ xbT,
                                              float* __restrict__ x2) {
  __shared__ ushort tile[64][68];
  const int b = blockIdx.z;
  const int o0 = blockIdx.y * 64;
  const int s0 = blockIdx.x * 64;
  const int t = threadIdx.x;
  const int tr = t >> 4;
  const int tc = t & 15;
#pragma unroll
  for (int p = 0; p < 4; ++p) {
    const int r = p * 16 + tr;
    f32x4v v = __builtin_nontemporal_load(
        ((const f32x4v*)(x + ((size_t)(b * K_DIM + o0 + r)) * N_DIM + s0)) + tc);
    tile[r][tc * 4 + 0] = f2bf(v.x);
    tile[r][tc * 4 + 1] = f2bf(v.y);
    tile[r][tc * 4 + 2] = f2bf(v.z);
    tile[r][tc * 4 + 3] = f2bf(v.w);
  }
  __syncthreads();
#pragma unroll
  for (int p = 0; p < 4; ++p) {
    const int s = p * 16 + tr;
    ushort u0 = tile[tc * 4 + 0][s];
    ushort u1 = tile[tc * 4 + 1][s];
    ushort u2 = tile[tc * 4 + 2][s];
    ushort u3 = tile[tc * 4 + 3][s];
    float f0 = bf2f(u0), f1 = bf2f(u1), f2 = bf2f(u2), f3 = bf2f(u3);
    float ss = f0 * f0 + f1 * f1 + f2 * f2 + f3 * f3;
#pragma unroll
    for (int m = 1; m < 16; m <<= 1) ss += __shfl_xor(ss, m);
    if (tc == 0) atomicAdd(&x2[b * N_DIM + s0 + s], ss);
    *(ushort4*)(xbT + ((size_t)(b * N_DIM + s0 + s)) * K_DIM + o0 + tc * 4) =
        make_ushort4(u0, u1, u2, u3);
  }
}

// -------- GEMM ---------------------------------------------------------------
typedef const __attribute__((address_space(1))) uint32_t* gp_t;
typedef __attribute__((address_space(3))) uint32_t* lp_t;

__device__ __forceinline__ void gload_lds16(const void* g, const void* l) {
  __builtin_amdgcn_global_load_lds((gp_t)(uintptr_t)g,
                                   (lp_t)(uint32_t)(uintptr_t)l, 16, 0, 0);
}

#define MFMA(a, b, c) __builtin_amdgcn_mfma_f32_16x16x32_bf16((a), (b), (c), 0, 0, 0)
#define FENCE() asm volatile("" ::: "memory")

__global__ __launch_bounds__(512, 2) void gemm_mse(
    const ushort* __restrict__ wbf, const ushort* __restrict__ xbT,
    const float* __restrict__ w2, const float* __restrict__ x2,
    float* __restrict__ out) {
  // LDS: A bufs 4x16KB at [0,64K), B bufs 4x16KB at [64K,128K)
  __shared__ __align__(16) char smem[131072];
  const int tid = threadIdx.x;
  const int wid = tid >> 6;
  const int lane = tid & 63;
  const int laneR = lane & 15;
  const int g = lane >> 4;
  const int wm = wid >> 2;  // 0..1
  const int wn = wid & 3;   // 0..3

  // XCD-aware block swizzle (512 blocks, 512%8==0 -> bijective)
  const int bid = blockIdx.x;
  const int swz = (bid & 7) * (MT * NT * B_DIM / 8) + (bid >> 3);
  const int m = swz & (MT - 1);
  const int nb = swz >> 4;
  const int n = nb & (NT - 1);
  const int bz = nb >> 3;

  const ushort* Ag = wbf + (size_t)m * BM * K_DIM;
  const ushort* Bg = xbT + ((size_t)bz * N_DIM + (size_t)n * BN) * K_DIM;

  // staging: slot s -> phys byte p=s*16; lin = p ^ (((p>>7)&3)<<4);
  // row = lin>>6 (64B = one 32-bf16 row), col = (lin&63)>>1
  const int p0 = tid * 16, p1 = (tid + 512) * 16;
  const int li0 = p0 ^ (((p0 >> 7) & 3) << 4);
  const int li1 = p1 ^ (((p1 >> 7) & 3) << 4);
  const size_t gOff0 = (size_t)(li0 >> 6) * K_DIM + ((li0 & 63) >> 1);
  const size_t gOff1 = (size_t)(li1 >> 6) * K_DIM + ((li1 & 63) >> 1);
  const int stA0 = wid * 1024, stA1 = 8192 + wid * 1024;
  const int stB0 = 65536 + wid * 1024, stB1 = 65536 + 8192 + wid * 1024;

#define STAGE_A(tt)                                    \
  {                                                    \
    const int bo_ = ((tt) & 3) * 16384;                \
    const int ko_ = (tt) * BK;                         \
    gload_lds16(Ag + gOff0 + ko_, smem + bo_ + stA0);  \
    gload_lds16(Ag + gOff1 + ko_, smem + bo_ + stA1);  \
  }
#define STAGE_B(tt)                                    \
  {                                                    \
    const int bo_ = ((tt) & 3) * 16384;                \
    const int ko_ = (tt) * BK;                         \
    gload_lds16(Bg + gOff0 + ko_, smem + bo_ + stB0);  \
    gload_lds16(Bg + gOff1 + ko_, smem + bo_ + stB1);  \
  }

  // frag bases: row-major [row][32 bf16]; mask = ((laneR>>1)&3)<<4
  const int mask = ((laneR >> 1) & 3) << 4;
  const int baseA = ((((wm * 128 + laneR) << 6) | (g << 4)) ^ mask);
  const int baseB = 65536 + ((((wn * 64 + laneR) << 6) | (g << 4)) ^ mask);

#define LDA(mi, bo) (*(const bf16x8*)(smem + (bo) + baseA + (mi)*1024))
#define LDB(ni, bo) (*(const bf16x8*)(smem + (bo) + baseB + (ni)*1024))

  f32x4 acc[8][4] = {};

  // prologue: stage tiles 0,1,2 (12 loads); tile 0 landed at vmcnt(8)
  STAGE_A(0); STAGE_B(0);
  STAGE_A(1); STAGE_B(1);
  STAGE_A(2); STAGE_B(2);
  asm volatile("s_waitcnt vmcnt(8)" ::: "memory");
  __builtin_amdgcn_s_barrier();
  FENCE();

  for (int t = 0; t < NKT; ++t) {
    const int bo = (t & 3) * 16384;
    // frag reads of tile t (visible since barrier at end of iter t-1)
    bf16x8 a0 = LDA(0, bo), a1 = LDA(1, bo), a2 = LDA(2, bo), a3 = LDA(3, bo);
    bf16x8 a4 = LDA(4, bo), a5 = LDA(5, bo), a6 = LDA(6, bo), a7 = LDA(7, bo);
    bf16x8 b0 = LDB(0, bo), b1 = LDB(1, bo), b2 = LDB(2, bo), b3 = LDB(3, bo);
    // stage tile t+3 into buf (t+3)&3 (= (t-1)&3, consumed & barrier-cleared).
    // Wraparound at the tail keeps the ledger uniform: 12 outstanding here.
    const int tt = (t + 3) & (NKT - 1);
    STAGE_A(tt); STAGE_B(tt);
    // counted wait: 12 -> 8 completes the 4 oldest = tile t+1 fully landed.
    asm volatile("s_waitcnt vmcnt(8)" ::: "memory");
    __builtin_amdgcn_s_setprio(1);
    acc[0][0] = MFMA(a0, b0, acc[0][0]);
    acc[0][1] = MFMA(a0, b1, acc[0][1]);
    acc[0][2] = MFMA(a0, b2, acc[0][2]);
    acc[0][3] = MFMA(a0, b3, acc[0][3]);
    acc[1][0] = MFMA(a1, b0, acc[1][0]);
    acc[1][1] = MFMA(a1, b1, acc[1][1]);
    acc[1][2] = MFMA(a1, b2, acc[1][2]);
    acc[1][3] = MFMA(a1, b3, acc[1][3]);
    acc[2][0] = MFMA(a2, b0, acc[2][0]);
    acc[2][1] = MFMA(a2, b1, acc[2][1]);
    acc[2][2] = MFMA(a2, b2, acc[2][2]);
    acc[2][3] = MFMA(a2, b3, acc[2][3]);
    acc[3][0] = MFMA(a3, b0, acc[3][0]);
    acc[3][1] = MFMA(a3, b1, acc[3][1]);
    acc[3][2] = MFMA(a3, b2, acc[3][2]);
    acc[3][3] = MFMA(a3, b3, acc[3][3]);
    acc[4][0] = MFMA(a4, b0, acc[4][0]);
    acc[4][1] = MFMA(a4, b1, acc[4][1]);
    acc[4][2] = MFMA(a4, b2, acc[4][2]);
    acc[4][3] = MFMA(a4, b3, acc[4][3]);
    acc[5][0] = MFMA(a5, b0, acc[5][0]);
    acc[5][1] = MFMA(a5, b1, acc[5][1]);
    acc[5][2] = MFMA(a5, b2, acc[5][2]);
    acc[5][3] = MFMA(a5, b3, acc[5][3]);
    acc[6][0] = MFMA(a6, b0, acc[6][0]);
    acc[6][1] = MFMA(a6, b1, acc[6][1]);
    acc[6][2] = MFMA(a6, b2, acc[6][2]);
    acc[6][3] = MFMA(a6, b3, acc[6][3]);
    acc[7][0] = MFMA(a7, b0, acc[7][0]);
    acc[7][1] = MFMA(a7, b1, acc[7][1]);
    acc[7][2] = MFMA(a7, b2, acc[7][2]);
    acc[7][3] = MFMA(a7, b3, acc[7][3]);
    __builtin_amdgcn_s_setprio(0);
    // prove all waves' LDS reads of buf t complete before iter t+1's staging
    // can overwrite it (stage t+4 -> buf t&3).
    asm volatile("s_waitcnt lgkmcnt(0)" ::: "memory");
    __builtin_amdgcn_sched_barrier(0);
    __builtin_amdgcn_s_barrier();
    FENCE();
  }

  // ==== epilogue: LDS-transpose -> coalesced 256B dwordx4 stores (no nt:
  // L2 absorbs at ~34 TB/s; nt-to-HBM was +11us in r6) ====
  asm volatile("s_waitcnt vmcnt(0)" ::: "memory");
  __builtin_amdgcn_s_barrier();
  FENCE();

  const float inv = 1.0f / (float)K_DIM;
  const int rowb0 = m * BM + wm * 128;  // wave's global row base
  const int colb0 = n * BN + wn * 64;   // wave's global col base
  float xv[4];
#pragma unroll
  for (int ni = 0; ni < 4; ++ni) xv[ni] = x2[bz * N_DIM + colb0 + ni * 16 + laneR];
  float* lds_f = (float*)smem + wid * 4096;  // 16 KB per wave, private
  float* outp = out + (size_t)bz * M_DIM * N_DIM;

#pragma unroll
  for (int miH = 0; miH < 2; ++miH) {
    // write pass: transform + transposed, bank-swizzled scatter
#pragma unroll
    for (int mi4 = 0; mi4 < 4; ++mi4) {
      const int mi = miH * 4 + mi4;
#pragma unroll
      for (int j = 0; j < 4; ++j) {
        const int r = mi4 * 16 + g * 4 + j;
        const float wv = w2[rowb0 + miH * 64 + r];
#pragma unroll
        for (int ni = 0; ni < 4; ++ni) {
          const int c = ni * 16 + laneR;
          lds_f[r * 64 + (c ^ ((r & 7) << 2))] =
              (wv - 2.0f * acc[mi][ni][j] + xv[ni]) * inv;
        }
      }
    }
    // read+store pass: 16 lanes cover 256B contiguous per row
#pragma unroll
    for (int k = 0; k < 16; ++k) {
      const int r = k * 4 + (lane >> 4);
      const int c0 = laneR * 4;
      f32x4 v = *(const f32x4*)&lds_f[r * 64 + (c0 ^ ((r & 7) << 2))];
      *(f32x4*)(outp + (size_t)(rowb0 + miH * 64 + r) * N_DIM + colb0 + c0) = v;
    }
  }
#undef STAGE_A
#undef STAGE_B
#undef LDA
#undef LDB
}

// -------- launcher -----------------------------------------------------------
extern "C" void kernel_launch(void* const* d_in, const int* in_sizes, int n_in,
                              void* d_out, int out_size, void* d_ws, size_t ws_size,
                              hipStream_t stream) {
  const float* x = (const float*)d_in[0];  // (4, 1024, 2048)
  const float* w = (const float*)d_in[1];  // (4096, 1024)
  float* out = (float*)d_out;              // (4, 4096, 2048)
  char* ws = (char*)d_ws;
  ushort* wbf = (ushort*)ws;                        // 8 MB
  ushort* xbT = (ushort*)(ws + (size_t)(8 << 20));  // 16 MB
  float* w2 = (float*)(ws + (size_t)(24 << 20));    // 16 KB
  float* x2 = w2 + M_DIM;                           // 32 KB

  prep_w<<<dim3(M_DIM), dim3(256), 0, stream>>>(w, wbf, w2, x2);
  prep_x<<<dim3(N_DIM / 64, K_DIM / 64, B_DIM), dim3(256), 0, stream>>>(x, xbT, x2);
  gemm_mse<<<dim3(MT * NT * B_DIM), dim3(512), 0, stream>>>(wbf, xbT, w2, x2, out);
}

// Round 8
// 98.312 us; speedup vs baseline: 1.3162x; 1.0413x over previous
//
#include <hip/hip_runtime.h>
#include <stdint.h>

// out[b,i,s] = (||w_i||^2 - 2*sum_o w[i,o]x[b,o,s] + ||x_{b,:,s}||^2) / K
// B=4, M=4096, K=1024, N=2048 (flattened N'=8192). fp32 in/out.
// R8: MX-fp8 cross term via mfma_scale_f32_16x16x128_f8f6f4 (unit scales),
// w stored as (w*64) e4m3, 1/64 folded into epilogue; w2/x2 exact fp32.
// GEMM: 128x256 tile, BK=128 (fp8 bytes), triple-buffered 48KB LDS,
// counted vmcnt(6), one barrier/K-tile, XOR swizzle (conflict-free),
// LDS-transpose epilogue with normal (L2-absorbed) stores.

#define M_DIM 4096
#define K_DIM 1024
#define N_DIM 2048
#define B_DIM 4
#define NF 8192  // flattened B*N

#define BM 128
#define BN 256
#define BK 128
#define NKT (K_DIM / BK)  // 8
#define MT (M_DIM / BM)   // 32
#define NT (NF / BN)      // 32
#define BUFB 49152        // 16KB A + 32KB B per buffer

typedef __attribute__((ext_vector_type(4))) int i32x4;
typedef __attribute__((ext_vector_type(8))) int i32x8;
typedef __attribute__((ext_vector_type(4))) float f32x4;
typedef __attribute__((ext_vector_type(4))) float f32x4v;

// -------- prep_w: w f32 [M][K] -> w8 = e4m3(w*64) [M][K]; w2 exact; x2=0 ----
__global__ __launch_bounds__(256) void prep_w(const float* __restrict__ w,
                                              uint8_t* __restrict__ w8,
                                              float* __restrict__ w2,
                                              float* __restrict__ x2) {
  const int i = blockIdx.x;
  const int t = threadIdx.x;
  if (i < 32) x2[i * 256 + t] = 0.0f;  // zero 8192 floats for prep_x atomics
  f32x4v v = __builtin_nontemporal_load(((const f32x4v*)(w + (size_t)i * K_DIM)) + t);
  float ss = v.x * v.x + v.y * v.y + v.z * v.z + v.w * v.w;
  uint32_t pk = 0;
  pk = __builtin_amdgcn_cvt_pk_fp8_f32(v.x * 64.0f, v.y * 64.0f, pk, false);
  pk = __builtin_amdgcn_cvt_pk_fp8_f32(v.z * 64.0f, v.w * 64.0f, pk, true);
  ((uint32_t*)(w8 + (size_t)i * K_DIM))[t] = pk;
#pragma unroll
  for (int off = 32; off > 0; off >>= 1) ss += __shfl_down(ss, off);
  __shared__ float red[4];
  if ((t & 63) == 0) red[t >> 6] = ss;
  __syncthreads();
  if (t == 0) w2[i] = red[0] + red[1] + red[2] + red[3];
}

// -------- prep_x: x f32 [B][K][N] -> x8 = e4m3(x) [B][N][K]; x2 exact -------
__global__ __launch_bounds__(256) void prep_x(const float* __restrict__ x,
                                              uint8_t* __restrict__ x8,
                                              float* __restrict__ x2) {
  __shared__ uint8_t tile[64][68];  // [o][s] fp8, pitch 68 (4-aligned)
  const int b = blockIdx.z;
  const int o0 = blockIdx.y * 64;
  const int s0 = blockIdx.x * 64;
  const int t = threadIdx.x;
  const int tr = t >> 4;
  const int tc = t & 15;
  float ss0 = 0, ss1 = 0, ss2 = 0, ss3 = 0;
#pragma unroll
  for (int p = 0; p < 4; ++p) {
    const int r = p * 16 + tr;
    f32x4v v = __builtin_nontemporal_load(
        ((const f32x4v*)(x + ((size_t)(b * K_DIM + o0 + r)) * N_DIM + s0)) + tc);
    ss0 += v.x * v.x; ss1 += v.y * v.y; ss2 += v.z * v.z; ss3 += v.w * v.w;
    uint32_t pk = 0;
    pk = __builtin_amdgcn_cvt_pk_fp8_f32(v.x, v.y, pk, false);
    pk = __builtin_amdgcn_cvt_pk_fp8_f32(v.z, v.w, pk, true);
    *(uint32_t*)&tile[r][tc * 4] = pk;
  }
  // exact x2 partials: reduce over tr within wave (lanes xor 16, 32)
  ss0 += __shfl_xor(ss0, 16); ss0 += __shfl_xor(ss0, 32);
  ss1 += __shfl_xor(ss1, 16); ss1 += __shfl_xor(ss1, 32);
  ss2 += __shfl_xor(ss2, 16); ss2 += __shfl_xor(ss2, 32);
  ss3 += __shfl_xor(ss3, 16); ss3 += __shfl_xor(ss3, 32);
  if ((t & 63) < 16) {
    float* xp = x2 + b * N_DIM + s0 + tc * 4;
    atomicAdd(xp + 0, ss0);
    atomicAdd(xp + 1, ss1);
    atomicAdd(xp + 2, ss2);
    atomicAdd(xp + 3, ss3);
  }
  __syncthreads();
  // transpose write: row s gets 64 contiguous fp8 (this o-block)
#pragma unroll
  for (int p = 0; p < 4; ++p) {
    const int s = p * 16 + tr;
    const int a = tc * 4;
    uint32_t o = (uint32_t)tile[a][s] | ((uint32_t)tile[a + 1][s] << 8) |
                 ((uint32_t)tile[a + 2][s] << 16) | ((uint32_t)tile[a + 3][s] << 24);
    *(uint32_t*)(x8 + ((size_t)(b * N_DIM + s0 + s)) * K_DIM + o0 + a) = o;
  }
}

// -------- GEMM (MX-fp8, unit scales) ----------------------------------------
typedef const __attribute__((address_space(1))) uint32_t* gp_t;
typedef __attribute__((address_space(3))) uint32_t* lp_t;

__device__ __forceinline__ void gload_lds16(const void* g, const void* l) {
  __builtin_amdgcn_global_load_lds((gp_t)(uintptr_t)g,
                                   (lp_t)(uint32_t)(uintptr_t)l, 16, 0, 0);
}

// fmt 0 = fp8 e4m3 for A and B; scales 127 = 2^0 (e8m0), opsel byte 0.
#define MFMA8(a, b, c) \
  __builtin_amdgcn_mfma_scale_f32_16x16x128_f8f6f4((a), (b), (c), 0, 0, 0, 127, 0, 127)
#define FENCE() asm volatile("" ::: "memory")

__global__ __launch_bounds__(512, 2) void gemm_mse8(
    const uint8_t* __restrict__ w8, const uint8_t* __restrict__ x8,
    const float* __restrict__ w2, const float* __restrict__ x2,
    float* __restrict__ out) {
  // LDS: 3 bufs x (A 16KB | B 32KB)
  __shared__ __align__(32) char smem[3 * BUFB];
  const int tid = threadIdx.x;
  const int wid = tid >> 6;
  const int lane = tid & 63;
  const int laneR = lane & 15;
  const int g = lane >> 4;
  const int wm = wid >> 2;  // 0..1 (64-row half of BM=128)
  const int wn = wid & 3;   // 0..3 (64-col quarter of BN=256)

  // XCD swizzle (1024 blocks, %8==0 -> bijective); m fastest (B-panel reuse)
  const int bid = blockIdx.x;
  const int swz = (bid & 7) * (MT * NT / 8) + (bid >> 3);
  const int mt = swz & (MT - 1);
  const int nt = swz >> 5;

  const uint8_t* Ag = w8 + (size_t)mt * BM * K_DIM;
  const uint8_t* Bg = x8 + (size_t)nt * BN * K_DIM;

  // staging: 6 x 16B chunks/thread; LDS linear slot p; source pre-swizzled:
  // logical (row,col) stored at phys row*128 + (col ^ ((row&7)<<4))
#define SRCOFF(P) ((size_t)((P) >> 7) * K_DIM + (((P) ^ ((((P) >> 7) & 7) << 4)) & 127))
  const int pa0 = tid * 16, pa1 = pa0 + 8192;          // A slots [0,16K)
  const int qb0 = tid * 16, qb1 = qb0 + 8192;          // B slots [0,32K)
  const int qb2 = qb0 + 16384, qb3 = qb0 + 24576;
  const uint8_t* sA0 = Ag + SRCOFF(pa0);
  const uint8_t* sA1 = Ag + SRCOFF(pa1);
  const uint8_t* sB0 = Bg + SRCOFF(qb0);
  const uint8_t* sB1 = Bg + SRCOFF(qb1);
  const uint8_t* sB2 = Bg + SRCOFF(qb2);
  const uint8_t* sB3 = Bg + SRCOFF(qb3);

#define STAGE(tt, buf)                                   \
  {                                                      \
    const int ko_ = (tt) * BK;                           \
    char* lb_ = smem + (buf) * BUFB;                     \
    gload_lds16(sA0 + ko_, lb_ + pa0);                   \
    gload_lds16(sA1 + ko_, lb_ + pa1);                   \
    gload_lds16(sB0 + ko_, lb_ + 16384 + qb0);           \
    gload_lds16(sB1 + ko_, lb_ + 16384 + qb1);           \
    gload_lds16(sB2 + ko_, lb_ + 16384 + qb2);           \
    gload_lds16(sB3 + ko_, lb_ + 16384 + qb3);           \
  }

  // frag reads: lane holds k-bytes [g*32, g*32+32) of row r; swizzled.
  // (r&7) == (laneR&7) since row-block bases are multiples of 8.
  const int tail0 = (g << 5) ^ ((laneR & 7) << 4);
  const int offA0 = (wm * 64 + 0 * 16 + laneR) * 128 + tail0;
  const int offB0 = 16384 + (wn * 64 + 0 * 16 + laneR) * 128 + tail0;

#define LDF(off, bo)                                                          \
  ({                                                                          \
    i32x4 lo_ = *(const i32x4*)(smem + (bo) + (off));                         \
    i32x4 hi_ = *(const i32x4*)(smem + (bo) + ((off) ^ 16));                  \
    (i32x8){lo_[0], lo_[1], lo_[2], lo_[3], hi_[0], hi_[1], hi_[2], hi_[3]};  \
  })

  f32x4 acc[4][4] = {};

  // prologue: stage tiles 0,1 (12 loads); tile 0 landed at vmcnt(6)
  STAGE(0, 0);
  STAGE(1, 1);
  asm volatile("s_waitcnt vmcnt(6)" ::: "memory");
  __builtin_amdgcn_s_barrier();
  FENCE();

#pragma unroll
  for (int t = 0; t < NKT; ++t) {
    const int bo = (t % 3) * BUFB;
    i32x8 a0 = LDF(offA0 + 0 * 2048, bo);
    i32x8 a1 = LDF(offA0 + 1 * 2048, bo);
    i32x8 a2 = LDF(offA0 + 2 * 2048, bo);
    i32x8 a3 = LDF(offA0 + 3 * 2048, bo);
    i32x8 b0 = LDF(offB0 + 0 * 2048, bo);
    i32x8 b1 = LDF(offB0 + 1 * 2048, bo);
    i32x8 b2 = LDF(offB0 + 2 * 2048, bo);
    i32x8 b3 = LDF(offB0 + 3 * 2048, bo);
    // stage tile t+2 into buf (t+2)%3 (overwrites buf (t-1)%3: its reads
    // drained before barrier@t-1). Wraparound keeps ledger uniform.
    STAGE((t + 2) & (NKT - 1), (t + 2) % 3);
    // counted: 12 outstanding -> 6 completes tile t+1; t+2 stays in flight.
    asm volatile("s_waitcnt vmcnt(6)" ::: "memory");
    __builtin_amdgcn_s_setprio(1);
    acc[0][0] = MFMA8(a0, b0, acc[0][0]);
    acc[0][1] = MFMA8(a0, b1, acc[0][1]);
    acc[0][2] = MFMA8(a0, b2, acc[0][2]);
    acc[0][3] = MFMA8(a0, b3, acc[0][3]);
    acc[1][0] = MFMA8(a1, b0, acc[1][0]);
    acc[1][1] = MFMA8(a1, b1, acc[1][1]);
    acc[1][2] = MFMA8(a1, b2, acc[1][2]);
    acc[1][3] = MFMA8(a1, b3, acc[1][3]);
    acc[2][0] = MFMA8(a2, b0, acc[2][0]);
    acc[2][1] = MFMA8(a2, b1, acc[2][1]);
    acc[2][2] = MFMA8(a2, b2, acc[2][2]);
    acc[2][3] = MFMA8(a2, b3, acc[2][3]);
    acc[3][0] = MFMA8(a3, b0, acc[3][0]);
    acc[3][1] = MFMA8(a3, b1, acc[3][1]);
    acc[3][2] = MFMA8(a3, b2, acc[3][2]);
    acc[3][3] = MFMA8(a3, b3, acc[3][3]);
    __builtin_amdgcn_s_setprio(0);
    asm volatile("s_waitcnt lgkmcnt(0)" ::: "memory");
    __builtin_amdgcn_sched_barrier(0);
    __builtin_amdgcn_s_barrier();
    FENCE();
  }

  // ==== epilogue: LDS-transpose -> coalesced 256B dwordx4 stores ====
  asm volatile("s_waitcnt vmcnt(0)" ::: "memory");
  __builtin_amdgcn_s_barrier();
  FENCE();

  // out = (w2 + x2 - acc/32) / 1024   [acc = 64*wx -> 2wx = acc/32]
  const float cA = 0.03125f;
  const float inv = 1.0f / (float)K_DIM;
  const int rowb0 = mt * BM + wm * 64;
  const int colf0 = nt * BN + wn * 64;  // flattened col in [0, 8192)
  const int bz = colf0 >> 11;
  const int sc0 = colf0 & (N_DIM - 1);
  float xv[4];
#pragma unroll
  for (int ni = 0; ni < 4; ++ni) xv[ni] = x2[colf0 + ni * 16 + laneR];
  float* lds_f = (float*)smem + wid * 4096;  // 16KB per wave, private
  float* outp = out + (size_t)bz * M_DIM * N_DIM;

#pragma unroll
  for (int mi = 0; mi < 4; ++mi) {
#pragma unroll
    for (int j = 0; j < 4; ++j) {
      const int r = mi * 16 + g * 4 + j;  // 0..63 (C/D: row=g*4+j, col=laneR)
      const float wv = w2[rowb0 + r];
#pragma unroll
      for (int ni = 0; ni < 4; ++ni) {
        const int c = ni * 16 + laneR;
        lds_f[r * 64 + (c ^ ((r & 7) << 2))] =
            (wv + xv[ni] - acc[mi][ni][j] * cA) * inv;
      }
    }
  }
#pragma unroll
  for (int k = 0; k < 16; ++k) {
    const int r = k * 4 + (lane >> 4);
    const int c0 = laneR * 4;
    f32x4 v = *(const f32x4*)&lds_f[r * 64 + (c0 ^ ((r & 7) << 2))];
    *(f32x4*)(outp + (size_t)(rowb0 + r) * N_DIM + sc0 + c0) = v;
  }
#undef STAGE
#undef LDF
#undef SRCOFF
}

// -------- launcher -----------------------------------------------------------
extern "C" void kernel_launch(void* const* d_in, const int* in_sizes, int n_in,
                              void* d_out, int out_size, void* d_ws, size_t ws_size,
                              hipStream_t stream) {
  const float* x = (const float*)d_in[0];  // (4, 1024, 2048)
  const float* w = (const float*)d_in[1];  // (4096, 1024)
  float* out = (float*)d_out;              // (4, 4096, 2048)
  char* ws = (char*)d_ws;
  uint8_t* w8 = (uint8_t*)ws;                       // 4 MB
  uint8_t* x8 = (uint8_t*)(ws + (size_t)(4 << 20)); // 8 MB
  float* w2 = (float*)(ws + (size_t)(12 << 20));    // 16 KB
  float* x2 = w2 + M_DIM;                           // 32 KB

  prep_w<<<dim3(M_DIM), dim3(256), 0, stream>>>(w, w8, w2, x2);
  prep_x<<<dim3(N_DIM / 64, K_DIM / 64, B_DIM), dim3(256), 0, stream>>>(x, x8, x2);
  gemm_mse8<<<dim3(MT * NT), dim3(512), 0, stream>>>(w8, x8, w2, x2, out);
}

// Round 9
// 98.220 us; speedup vs baseline: 1.3174x; 1.0009x over previous
//
#include <hip/hip_runtime.h>
#include <stdint.h>

// out[b,i,s] = (||w_i||^2 - 2*sum_o w[i,o]x[b,o,s] + ||x_{b,:,s}||^2) / K
// B=4, M=4096, K=1024, N=2048 (flattened N'=8192). fp32 in/out.
// MX-fp8 cross term (mfma_scale 16x16x128, unit scales); w2/x2 exact fp32.
// 128x256 tile, BK=128B, triple-buffered LDS, one barrier/K-tile.
// R9: counted vmcnt(6) moved AFTER the MFMA cluster (hide next-tile staging
// latency under compute); STAGE issued before frag reads.

#define M_DIM 4096
#define K_DIM 1024
#define N_DIM 2048
#define B_DIM 4
#define NF 8192  // flattened B*N

#define BM 128
#define BN 256
#define BK 128
#define NKT (K_DIM / BK)  // 8
#define MT (M_DIM / BM)   // 32
#define NT (NF / BN)      // 32
#define BUFB 49152        // 16KB A + 32KB B per buffer

typedef __attribute__((ext_vector_type(4))) int i32x4;
typedef __attribute__((ext_vector_type(8))) int i32x8;
typedef __attribute__((ext_vector_type(4))) float f32x4;
typedef __attribute__((ext_vector_type(4))) float f32x4v;

// -------- prep_w: w f32 [M][K] -> w8 = e4m3(w*64) [M][K]; w2 exact; x2=0 ----
__global__ __launch_bounds__(256) void prep_w(const float* __restrict__ w,
                                              uint8_t* __restrict__ w8,
                                              float* __restrict__ w2,
                                              float* __restrict__ x2) {
  const int i = blockIdx.x;
  const int t = threadIdx.x;
  if (i < 32) x2[i * 256 + t] = 0.0f;  // zero 8192 floats for prep_x atomics
  f32x4v v = __builtin_nontemporal_load(((const f32x4v*)(w + (size_t)i * K_DIM)) + t);
  float ss = v.x * v.x + v.y * v.y + v.z * v.z + v.w * v.w;
  uint32_t pk = 0;
  pk = __builtin_amdgcn_cvt_pk_fp8_f32(v.x * 64.0f, v.y * 64.0f, pk, false);
  pk = __builtin_amdgcn_cvt_pk_fp8_f32(v.z * 64.0f, v.w * 64.0f, pk, true);
  ((uint32_t*)(w8 + (size_t)i * K_DIM))[t] = pk;
#pragma unroll
  for (int off = 32; off > 0; off >>= 1) ss += __shfl_down(ss, off);
  __shared__ float red[4];
  if ((t & 63) == 0) red[t >> 6] = ss;
  __syncthreads();
  if (t == 0) w2[i] = red[0] + red[1] + red[2] + red[3];
}

// -------- prep_x: x f32 [B][K][N] -> x8 = e4m3(x) [B][N][K]; x2 exact -------
__global__ __launch_bounds__(256) void prep_x(const float* __restrict__ x,
                                              uint8_t* __restrict__ x8,
                                              float* __restrict__ x2) {
  __shared__ uint8_t tile[64][68];  // [o][s] fp8, pitch 68 (4-aligned)
  const int b = blockIdx.z;
  const int o0 = blockIdx.y * 64;
  const int s0 = blockIdx.x * 64;
  const int t = threadIdx.x;
  const int tr = t >> 4;
  const int tc = t & 15;
  float ss0 = 0, ss1 = 0, ss2 = 0, ss3 = 0;
#pragma unroll
  for (int p = 0; p < 4; ++p) {
    const int r = p * 16 + tr;
    f32x4v v = __builtin_nontemporal_load(
        ((const f32x4v*)(x + ((size_t)(b * K_DIM + o0 + r)) * N_DIM + s0)) + tc);
    ss0 += v.x * v.x; ss1 += v.y * v.y; ss2 += v.z * v.z; ss3 += v.w * v.w;
    uint32_t pk = 0;
    pk = __builtin_amdgcn_cvt_pk_fp8_f32(v.x, v.y, pk, false);
    pk = __builtin_amdgcn_cvt_pk_fp8_f32(v.z, v.w, pk, true);
    *(uint32_t*)&tile[r][tc * 4] = pk;
  }
  // exact x2 partials: reduce over tr within wave (lanes xor 16, 32)
  ss0 += __shfl_xor(ss0, 16); ss0 += __shfl_xor(ss0, 32);
  ss1 += __shfl_xor(ss1, 16); ss1 += __shfl_xor(ss1, 32);
  ss2 += __shfl_xor(ss2, 16); ss2 += __shfl_xor(ss2, 32);
  ss3 += __shfl_xor(ss3, 16); ss3 += __shfl_xor(ss3, 32);
  if ((t & 63) < 16) {
    float* xp = x2 + b * N_DIM + s0 + tc * 4;
    atomicAdd(xp + 0, ss0);
    atomicAdd(xp + 1, ss1);
    atomicAdd(xp + 2, ss2);
    atomicAdd(xp + 3, ss3);
  }
  __syncthreads();
  // transpose write: row s gets 64 contiguous fp8 (this o-block)
#pragma unroll
  for (int p = 0; p < 4; ++p) {
    const int s = p * 16 + tr;
    const int a = tc * 4;
    uint32_t o = (uint32_t)tile[a][s] | ((uint32_t)tile[a + 1][s] << 8) |
                 ((uint32_t)tile[a + 2][s] << 16) | ((uint32_t)tile[a + 3][s] << 24);
    *(uint32_t*)(x8 + ((size_t)(b * N_DIM + s0 + s)) * K_DIM + o0 + a) = o;
  }
}

// -------- GEMM (MX-fp8, unit scales) ----------------------------------------
typedef const __attribute__((address_space(1))) uint32_t* gp_t;
typedef __attribute__((address_space(3))) uint32_t* lp_t;

__device__ __forceinline__ void gload_lds16(const void* g, const void* l) {
  __builtin_amdgcn_global_load_lds((gp_t)(uintptr_t)g,
                                   (lp_t)(uint32_t)(uintptr_t)l, 16, 0, 0);
}

// fmt 0 = fp8 e4m3 for A and B; scales 127 = 2^0 (e8m0).
#define MFMA8(a, b, c) \
  __builtin_amdgcn_mfma_scale_f32_16x16x128_f8f6f4((a), (b), (c), 0, 0, 0, 127, 0, 127)
#define FENCE() asm volatile("" ::: "memory")

__global__ __launch_bounds__(512, 2) void gemm_mse8(
    const uint8_t* __restrict__ w8, const uint8_t* __restrict__ x8,
    const float* __restrict__ w2, const float* __restrict__ x2,
    float* __restrict__ out) {
  // LDS: 3 bufs x (A 16KB | B 32KB)
  __shared__ __align__(32) char smem[3 * BUFB];
  const int tid = threadIdx.x;
  const int wid = tid >> 6;
  const int lane = tid & 63;
  const int laneR = lane & 15;
  const int g = lane >> 4;
  const int wm = wid >> 2;  // 0..1 (64-row half of BM=128)
  const int wn = wid & 3;   // 0..3 (64-col quarter of BN=256)

  // XCD swizzle (1024 blocks, %8==0 -> bijective); m fastest (B-panel reuse)
  const int bid = blockIdx.x;
  const int swz = (bid & 7) * (MT * NT / 8) + (bid >> 3);
  const int mt = swz & (MT - 1);
  const int nt = swz >> 5;

  const uint8_t* Ag = w8 + (size_t)mt * BM * K_DIM;
  const uint8_t* Bg = x8 + (size_t)nt * BN * K_DIM;

  // staging: 6 x 16B chunks/thread; LDS linear slot p; source pre-swizzled:
  // logical (row,col) stored at phys row*128 + (col ^ ((row&7)<<4))
#define SRCOFF(P) ((size_t)((P) >> 7) * K_DIM + (((P) ^ ((((P) >> 7) & 7) << 4)) & 127))
  const int pa0 = tid * 16, pa1 = pa0 + 8192;          // A slots [0,16K)
  const int qb0 = tid * 16, qb1 = qb0 + 8192;          // B slots [0,32K)
  const int qb2 = qb0 + 16384, qb3 = qb0 + 24576;
  const uint8_t* sA0 = Ag + SRCOFF(pa0);
  const uint8_t* sA1 = Ag + SRCOFF(pa1);
  const uint8_t* sB0 = Bg + SRCOFF(qb0);
  const uint8_t* sB1 = Bg + SRCOFF(qb1);
  const uint8_t* sB2 = Bg + SRCOFF(qb2);
  const uint8_t* sB3 = Bg + SRCOFF(qb3);

#define STAGE(tt, buf)                                   \
  {                                                      \
    const int ko_ = (tt) * BK;                           \
    char* lb_ = smem + (buf) * BUFB;                     \
    gload_lds16(sA0 + ko_, lb_ + pa0);                   \
    gload_lds16(sA1 + ko_, lb_ + pa1);                   \
    gload_lds16(sB0 + ko_, lb_ + 16384 + qb0);           \
    gload_lds16(sB1 + ko_, lb_ + 16384 + qb1);           \
    gload_lds16(sB2 + ko_, lb_ + 16384 + qb2);           \
    gload_lds16(sB3 + ko_, lb_ + 16384 + qb3);           \
  }

  // frag reads: lane holds k-bytes [g*32, g*32+32) of row r; swizzled.
  const int tail0 = (g << 5) ^ ((laneR & 7) << 4);
  const int offA0 = (wm * 64 + laneR) * 128 + tail0;
  const int offB0 = 16384 + (wn * 64 + laneR) * 128 + tail0;

#define LDF(off, bo)                                                          \
  ({                                                                          \
    i32x4 lo_ = *(const i32x4*)(smem + (bo) + (off));                         \
    i32x4 hi_ = *(const i32x4*)(smem + (bo) + ((off) ^ 16));                  \
    (i32x8){lo_[0], lo_[1], lo_[2], lo_[3], hi_[0], hi_[1], hi_[2], hi_[3]};  \
  })

  f32x4 acc[4][4] = {};

  // prologue: stage tiles 0,1 (12 loads); tile 0 landed at vmcnt(6)
  STAGE(0, 0);
  STAGE(1, 1);
  asm volatile("s_waitcnt vmcnt(6)" ::: "memory");
  __builtin_amdgcn_s_barrier();
  FENCE();

#pragma unroll
  for (int t = 0; t < NKT; ++t) {
    const int bo = (t % 3) * BUFB;
    // issue next-next tile staging FIRST (loads in flight under compute);
    // buf (t+2)%3 == (t-1)%3: reads drained before barrier at end of t-1.
    STAGE((t + 2) & (NKT - 1), (t + 2) % 3);
    i32x8 a0 = LDF(offA0 + 0 * 2048, bo);
    i32x8 a1 = LDF(offA0 + 1 * 2048, bo);
    i32x8 a2 = LDF(offA0 + 2 * 2048, bo);
    i32x8 a3 = LDF(offA0 + 3 * 2048, bo);
    i32x8 b0 = LDF(offB0 + 0 * 2048, bo);
    i32x8 b1 = LDF(offB0 + 1 * 2048, bo);
    i32x8 b2 = LDF(offB0 + 2 * 2048, bo);
    i32x8 b3 = LDF(offB0 + 3 * 2048, bo);
    __builtin_amdgcn_s_setprio(1);
    acc[0][0] = MFMA8(a0, b0, acc[0][0]);
    acc[0][1] = MFMA8(a0, b1, acc[0][1]);
    acc[0][2] = MFMA8(a0, b2, acc[0][2]);
    acc[0][3] = MFMA8(a0, b3, acc[0][3]);
    acc[1][0] = MFMA8(a1, b0, acc[1][0]);
    acc[1][1] = MFMA8(a1, b1, acc[1][1]);
    acc[1][2] = MFMA8(a1, b2, acc[1][2]);
    acc[1][3] = MFMA8(a1, b3, acc[1][3]);
    acc[2][0] = MFMA8(a2, b0, acc[2][0]);
    acc[2][1] = MFMA8(a2, b1, acc[2][1]);
    acc[2][2] = MFMA8(a2, b2, acc[2][2]);
    acc[2][3] = MFMA8(a2, b3, acc[2][3]);
    acc[3][0] = MFMA8(a3, b0, acc[3][0]);
    acc[3][1] = MFMA8(a3, b1, acc[3][1]);
    acc[3][2] = MFMA8(a3, b2, acc[3][2]);
    acc[3][3] = MFMA8(a3, b3, acc[3][3]);
    __builtin_amdgcn_s_setprio(0);
    // NOW wait: tile t+1 landed (12 outstanding -> 6 = tile t+2 only).
    // Compute above (~600cy) hid the staging latency.
    asm volatile("s_waitcnt vmcnt(6)" ::: "memory");
    // prove all waves' LDS reads of buf t done before iter t+1 stages into
    // buf t%3... (stage t+3 -> buf t%3) -- drained here, published by barrier.
    asm volatile("s_waitcnt lgkmcnt(0)" ::: "memory");
    __builtin_amdgcn_sched_barrier(0);
    __builtin_amdgcn_s_barrier();
    FENCE();
  }

  // ==== epilogue: LDS-transpose -> coalesced 256B dwordx4 stores ====
  asm volatile("s_waitcnt vmcnt(0)" ::: "memory");
  __builtin_amdgcn_s_barrier();
  FENCE();

  // out = (w2 + x2 - acc/32) / 1024   [acc = 64*wx -> 2wx = acc/32]
  const float cA = 0.03125f;
  const float inv = 1.0f / (float)K_DIM;
  const int rowb0 = mt * BM + wm * 64;
  const int colf0 = nt * BN + wn * 64;  // flattened col in [0, 8192)
  const int bz = colf0 >> 11;
  const int sc0 = colf0 & (N_DIM - 1);
  float xv[4];
#pragma unroll
  for (int ni = 0; ni < 4; ++ni) xv[ni] = x2[colf0 + ni * 16 + laneR];
  float* lds_f = (float*)smem + wid * 4096;  // 16KB per wave, private
  float* outp = out + (size_t)bz * M_DIM * N_DIM;

#pragma unroll
  for (int mi = 0; mi < 4; ++mi) {
#pragma unroll
    for (int j = 0; j < 4; ++j) {
      const int r = mi * 16 + g * 4 + j;  // C/D: row=g*4+j (+16mi), col=laneR
      const float wv = w2[rowb0 + r];
#pragma unroll
      for (int ni = 0; ni < 4; ++ni) {
        const int c = ni * 16 + laneR;
        lds_f[r * 64 + (c ^ ((r & 7) << 2))] =
            (wv + xv[ni] - acc[mi][ni][j] * cA) * inv;
      }
    }
  }
#pragma unroll
  for (int k = 0; k < 16; ++k) {
    const int r = k * 4 + (lane >> 4);
    const int c0 = laneR * 4;
    f32x4 v = *(const f32x4*)&lds_f[r * 64 + (c0 ^ ((r & 7) << 2))];
    *(f32x4*)(outp + (size_t)(rowb0 + r) * N_DIM + sc0 + c0) = v;
  }
#undef STAGE
#undef LDF
#undef SRCOFF
}

// -------- launcher -----------------------------------------------------------
extern "C" void kernel_launch(void* const* d_in, const int* in_sizes, int n_in,
                              void* d_out, int out_size, void* d_ws, size_t ws_size,
                              hipStream_t stream) {
  const float* x = (const float*)d_in[0];  // (4, 1024, 2048)
  const float* w = (const float*)d_in[1];  // (4096, 1024)
  float* out = (float*)d_out;              // (4, 4096, 2048)
  char* ws = (char*)d_ws;
  uint8_t* w8 = (uint8_t*)ws;                       // 4 MB
  uint8_t* x8 = (uint8_t*)(ws + (size_t)(4 << 20)); // 8 MB
  float* w2 = (float*)(ws + (size_t)(12 << 20));    // 16 KB
  float* x2 = w2 + M_DIM;                           // 32 KB

  prep_w<<<dim3(M_DIM), dim3(256), 0, stream>>>(w, w8, w2, x2);
  prep_x<<<dim3(N_DIM / 64, K_DIM / 64, B_DIM), dim3(256), 0, stream>>>(x, x8, x2);
  gemm_mse8<<<dim3(MT * NT), dim3(512), 0, stream>>>(w8, x8, w2, x2, out);
}

// Round 10
// 88.078 us; speedup vs baseline: 1.4691x; 1.1152x over previous
//
#include <hip/hip_runtime.h>
#include <stdint.h>

// out[b,i,s] = (||w_i||^2 - 2*sum_o w[i,o]x[b,o,s] + ||x_{b,:,s}||^2) / K
// B=4, M=4096, K=1024, N=2048 (flattened N'=8192). fp32 in/out.
// MX-fp8 cross term (mfma_scale 16x16x128, unit scales); w2/x2 exact fp32.
// R10: 256x256 tile, BK=128, 8 waves x (128x64 out) -> 1.33x less LDS frag
// traffic; double-buffered 2x64KB LDS; distance-1 prefetch with vmcnt(0)
// after compute; 512 blocks = 2 passes/CU.

#define M_DIM 4096
#define K_DIM 1024
#define N_DIM 2048
#define B_DIM 4
#define NF 8192  // flattened B*N

#define BM 256
#define BN 256
#define BK 128
#define NKT (K_DIM / BK)  // 8
#define MT (M_DIM / BM)   // 16
#define NT (NF / BN)      // 32
#define BUFB 65536        // 32KB A + 32KB B per buffer

typedef __attribute__((ext_vector_type(4))) int i32x4;
typedef __attribute__((ext_vector_type(8))) int i32x8;
typedef __attribute__((ext_vector_type(4))) float f32x4;
typedef __attribute__((ext_vector_type(4))) float f32x4v;

// -------- prep_w: w f32 [M][K] -> w8 = e4m3(w*64) [M][K]; w2 exact; x2=0 ----
__global__ __launch_bounds__(256) void prep_w(const float* __restrict__ w,
                                              uint8_t* __restrict__ w8,
                                              float* __restrict__ w2,
                                              float* __restrict__ x2) {
  const int i = blockIdx.x;
  const int t = threadIdx.x;
  if (i < 32) x2[i * 256 + t] = 0.0f;  // zero 8192 floats for prep_x atomics
  f32x4v v = __builtin_nontemporal_load(((const f32x4v*)(w + (size_t)i * K_DIM)) + t);
  float ss = v.x * v.x + v.y * v.y + v.z * v.z + v.w * v.w;
  uint32_t pk = 0;
  pk = __builtin_amdgcn_cvt_pk_fp8_f32(v.x * 64.0f, v.y * 64.0f, pk, false);
  pk = __builtin_amdgcn_cvt_pk_fp8_f32(v.z * 64.0f, v.w * 64.0f, pk, true);
  ((uint32_t*)(w8 + (size_t)i * K_DIM))[t] = pk;
#pragma unroll
  for (int off = 32; off > 0; off >>= 1) ss += __shfl_down(ss, off);
  __shared__ float red[4];
  if ((t & 63) == 0) red[t >> 6] = ss;
  __syncthreads();
  if (t == 0) w2[i] = red[0] + red[1] + red[2] + red[3];
}

// -------- prep_x: x f32 [B][K][N] -> x8 = e4m3(x) [B][N][K]; x2 exact -------
__global__ __launch_bounds__(256) void prep_x(const float* __restrict__ x,
                                              uint8_t* __restrict__ x8,
                                              float* __restrict__ x2) {
  __shared__ uint8_t tile[64][68];  // [o][s] fp8, pitch 68 (4-aligned)
  const int b = blockIdx.z;
  const int o0 = blockIdx.y * 64;
  const int s0 = blockIdx.x * 64;
  const int t = threadIdx.x;
  const int tr = t >> 4;
  const int tc = t & 15;
  float ss0 = 0, ss1 = 0, ss2 = 0, ss3 = 0;
#pragma unroll
  for (int p = 0; p < 4; ++p) {
    const int r = p * 16 + tr;
    f32x4v v = __builtin_nontemporal_load(
        ((const f32x4v*)(x + ((size_t)(b * K_DIM + o0 + r)) * N_DIM + s0)) + tc);
    ss0 += v.x * v.x; ss1 += v.y * v.y; ss2 += v.z * v.z; ss3 += v.w * v.w;
    uint32_t pk = 0;
    pk = __builtin_amdgcn_cvt_pk_fp8_f32(v.x, v.y, pk, false);
    pk = __builtin_amdgcn_cvt_pk_fp8_f32(v.z, v.w, pk, true);
    *(uint32_t*)&tile[r][tc * 4] = pk;
  }
  ss0 += __shfl_xor(ss0, 16); ss0 += __shfl_xor(ss0, 32);
  ss1 += __shfl_xor(ss1, 16); ss1 += __shfl_xor(ss1, 32);
  ss2 += __shfl_xor(ss2, 16); ss2 += __shfl_xor(ss2, 32);
  ss3 += __shfl_xor(ss3, 16); ss3 += __shfl_xor(ss3, 32);
  if ((t & 63) < 16) {
    float* xp = x2 + b * N_DIM + s0 + tc * 4;
    atomicAdd(xp + 0, ss0);
    atomicAdd(xp + 1, ss1);
    atomicAdd(xp + 2, ss2);
    atomicAdd(xp + 3, ss3);
  }
  __syncthreads();
#pragma unroll
  for (int p = 0; p < 4; ++p) {
    const int s = p * 16 + tr;
    const int a = tc * 4;
    uint32_t o = (uint32_t)tile[a][s] | ((uint32_t)tile[a + 1][s] << 8) |
                 ((uint32_t)tile[a + 2][s] << 16) | ((uint32_t)tile[a + 3][s] << 24);
    *(uint32_t*)(x8 + ((size_t)(b * N_DIM + s0 + s)) * K_DIM + o0 + a) = o;
  }
}

// -------- GEMM (MX-fp8, unit scales) ----------------------------------------
typedef const __attribute__((address_space(1))) uint32_t* gp_t;
typedef __attribute__((address_space(3))) uint32_t* lp_t;

__device__ __forceinline__ void gload_lds16(const void* g, const void* l) {
  __builtin_amdgcn_global_load_lds((gp_t)(uintptr_t)g,
                                   (lp_t)(uint32_t)(uintptr_t)l, 16, 0, 0);
}

// fmt 0 = fp8 e4m3 for A and B; scales 127 = 2^0 (e8m0).
#define MFMA8(a, b, c) \
  __builtin_amdgcn_mfma_scale_f32_16x16x128_f8f6f4((a), (b), (c), 0, 0, 0, 127, 0, 127)
#define FENCE() asm volatile("" ::: "memory")

__global__ __launch_bounds__(512) void gemm_mse8(
    const uint8_t* __restrict__ w8, const uint8_t* __restrict__ x8,
    const float* __restrict__ w2, const float* __restrict__ x2,
    float* __restrict__ out) {
  // LDS: 2 bufs x (A 32KB | B 32KB) = 128KB
  __shared__ __align__(32) char smem[2 * BUFB];
  const int tid = threadIdx.x;
  const int wid = tid >> 6;
  const int lane = tid & 63;
  const int laneR = lane & 15;
  const int g = lane >> 4;
  const int wm = wid >> 2;  // 0..1 (128-row half of BM=256)
  const int wn = wid & 3;   // 0..3 (64-col quarter of BN=256)

  // XCD swizzle (512 blocks, %8==0 -> bijective); m fastest (B-panel reuse)
  const int bid = blockIdx.x;
  const int swz = (bid & 7) * (MT * NT / 8) + (bid >> 3);
  const int mt = swz & (MT - 1);
  const int nt = swz >> 4;

  const uint8_t* Ag = w8 + (size_t)mt * BM * K_DIM;
  const uint8_t* Bg = x8 + (size_t)nt * BN * K_DIM;

  // staging: 8 x 16B chunks/thread (A 4, B 4); LDS linear slot p; source
  // pre-swizzled: logical (row,col) -> phys row*128 + (col ^ ((row&7)<<4))
#define SRCOFF(P) ((size_t)((P) >> 7) * K_DIM + (((P) ^ ((((P) >> 7) & 7) << 4)) & 127))
  const int p0 = tid * 16;
  const uint8_t* sA0 = Ag + SRCOFF(p0);
  const uint8_t* sA1 = Ag + SRCOFF(p0 + 8192);
  const uint8_t* sA2 = Ag + SRCOFF(p0 + 16384);
  const uint8_t* sA3 = Ag + SRCOFF(p0 + 24576);
  const uint8_t* sB0 = Bg + SRCOFF(p0);
  const uint8_t* sB1 = Bg + SRCOFF(p0 + 8192);
  const uint8_t* sB2 = Bg + SRCOFF(p0 + 16384);
  const uint8_t* sB3 = Bg + SRCOFF(p0 + 24576);

#define STAGE(tt, buf)                                   \
  {                                                      \
    const int ko_ = (tt) * BK;                           \
    char* lb_ = smem + (buf) * BUFB;                     \
    gload_lds16(sA0 + ko_, lb_ + p0);                    \
    gload_lds16(sA1 + ko_, lb_ + p0 + 8192);             \
    gload_lds16(sA2 + ko_, lb_ + p0 + 16384);            \
    gload_lds16(sA3 + ko_, lb_ + p0 + 24576);            \
    gload_lds16(sB0 + ko_, lb_ + 32768 + p0);            \
    gload_lds16(sB1 + ko_, lb_ + 32768 + p0 + 8192);     \
    gload_lds16(sB2 + ko_, lb_ + 32768 + p0 + 16384);    \
    gload_lds16(sB3 + ko_, lb_ + 32768 + p0 + 24576);    \
  }

  // frag reads: lane holds k-bytes [g*32,+32) of its row; row&7 == laneR&7
  const int tail = (g << 5) ^ ((laneR & 7) << 4);
  const int offA0 = (wm * 128 + laneR) * 128 + tail;            // + mi*2048
  const int offB0 = 32768 + (wn * 64 + laneR) * 128 + tail;     // + ni*2048

#define LDF(off, bo)                                                          \
  ({                                                                          \
    i32x4 lo_ = *(const i32x4*)(smem + (bo) + (off));                         \
    i32x4 hi_ = *(const i32x4*)(smem + (bo) + ((off) ^ 16));                  \
    (i32x8){lo_[0], lo_[1], lo_[2], lo_[3], hi_[0], hi_[1], hi_[2], hi_[3]};  \
  })

  f32x4 acc[8][4] = {};

  // prologue: stage tile 0
  STAGE(0, 0);
  asm volatile("s_waitcnt vmcnt(0)" ::: "memory");
  __builtin_amdgcn_s_barrier();
  FENCE();

#pragma unroll
  for (int t = 0; t < NKT; ++t) {
    const int bo = (t & 1) * BUFB;
    // issue next-tile staging first; its buf was consumed & barrier-cleared
    if (t < NKT - 1) STAGE(t + 1, (t + 1) & 1);
    i32x8 b0 = LDF(offB0 + 0 * 2048, bo);
    i32x8 b1 = LDF(offB0 + 1 * 2048, bo);
    i32x8 b2 = LDF(offB0 + 2 * 2048, bo);
    i32x8 b3 = LDF(offB0 + 3 * 2048, bo);
    __builtin_amdgcn_s_setprio(1);
#pragma unroll
    for (int mi = 0; mi < 8; ++mi) {
      i32x8 am = LDF(offA0 + mi * 2048, bo);
      acc[mi][0] = MFMA8(am, b0, acc[mi][0]);
      acc[mi][1] = MFMA8(am, b1, acc[mi][1]);
      acc[mi][2] = MFMA8(am, b2, acc[mi][2]);
      acc[mi][3] = MFMA8(am, b3, acc[mi][3]);
    }
    __builtin_amdgcn_s_setprio(0);
    // next tile landed (compute ~2200cy covered L2 latency + BW)
    asm volatile("s_waitcnt vmcnt(0)" ::: "memory");
    // all waves' reads of buf t done before iter t+1 stages into buf t&1
    asm volatile("s_waitcnt lgkmcnt(0)" ::: "memory");
    __builtin_amdgcn_sched_barrier(0);
    __builtin_amdgcn_s_barrier();
    FENCE();
  }

  // ==== epilogue: per-wave LDS-transpose (2x 64x64 halves, 16KB/wave) ====
  // out = (w2 + x2 - acc/32) / 1024   [acc = 64*wx -> 2wx = acc/32]
  const float cA = 0.03125f;
  const float inv = 1.0f / (float)K_DIM;
  const int rowb0 = mt * BM + wm * 128;
  const int colf0 = nt * BN + wn * 64;  // flattened col in [0, 8192)
  const int bz = colf0 >> 11;
  const int sc0 = colf0 & (N_DIM - 1);
  float xv[4];
#pragma unroll
  for (int ni = 0; ni < 4; ++ni) xv[ni] = x2[colf0 + ni * 16 + laneR];
  float* lds_f = (float*)smem + wid * 4096;  // 16KB per wave, private
  float* outp = out + (size_t)bz * M_DIM * N_DIM;

#pragma unroll
  for (int miH = 0; miH < 2; ++miH) {
#pragma unroll
    for (int mi4 = 0; mi4 < 4; ++mi4) {
      const int mi = miH * 4 + mi4;
#pragma unroll
      for (int j = 0; j < 4; ++j) {
        const int r = mi4 * 16 + g * 4 + j;  // local 0..63
        const float wv = w2[rowb0 + miH * 64 + r];
#pragma unroll
        for (int ni = 0; ni < 4; ++ni) {
          const int c = ni * 16 + laneR;
          lds_f[r * 64 + (c ^ ((r & 7) << 2))] =
              (wv + xv[ni] - acc[mi][ni][j] * cA) * inv;
        }
      }
    }
#pragma unroll
    for (int k = 0; k < 16; ++k) {
      const int r = k * 4 + (lane >> 4);
      const int c0 = laneR * 4;
      f32x4 v = *(const f32x4*)&lds_f[r * 64 + (c0 ^ ((r & 7) << 2))];
      *(f32x4*)(outp + (size_t)(rowb0 + miH * 64 + r) * N_DIM + sc0 + c0) = v;
    }
    // wave-private region; no cross-wave hazard -> no barrier. LDS reads of
    // this half complete before rewrite (same-wave program order via lgkm).
    asm volatile("s_waitcnt lgkmcnt(0)" ::: "memory");
  }
#undef STAGE
#undef LDF
#undef SRCOFF
}

// -------- launcher -----------------------------------------------------------
extern "C" void kernel_launch(void* const* d_in, const int* in_sizes, int n_in,
                              void* d_out, int out_size, void* d_ws, size_t ws_size,
                              hipStream_t stream) {
  const float* x = (const float*)d_in[0];  // (4, 1024, 2048)
  const float* w = (const float*)d_in[1];  // (4096, 1024)
  float* out = (float*)d_out;              // (4, 4096, 2048)
  char* ws = (char*)d_ws;
  uint8_t* w8 = (uint8_t*)ws;                       // 4 MB
  uint8_t* x8 = (uint8_t*)(ws + (size_t)(4 << 20)); // 8 MB
  float* w2 = (float*)(ws + (size_t)(12 << 20));    // 16 KB
  float* x2 = w2 + M_DIM;                           // 32 KB

  prep_w<<<dim3(M_DIM), dim3(256), 0, stream>>>(w, w8, w2, x2);
  prep_x<<<dim3(N_DIM / 64, K_DIM / 64, B_DIM), dim3(256), 0, stream>>>(x, x8, x2);
  gemm_mse8<<<dim3(MT * NT), dim3(512), 0, stream>>>(w8, x8, w2, x2, out);
}